// Round 4
// baseline (29780.884 us; speedup 1.0000x reference)
//
#include <hip/hip_runtime.h>
#include <hip/hip_cooperative_groups.h>
#include <stdint.h>

#define NBLK 256
#define NTHR 512          // 8 waves: K-split within block
#define BATCH 64
#define HD 1024
#define SEQ 512

typedef unsigned short u16;
typedef uint32_t u32;
typedef __attribute__((ext_vector_type(8))) short v8s;        // 8 bf16 (MFMA A/B frag)
typedef __attribute__((ext_vector_type(4))) float v4f;        // MFMA C/D frag
typedef __attribute__((ext_vector_type(4))) unsigned int v4u; // dwordx4
typedef __attribute__((ext_vector_type(2))) unsigned int v2u; // dwordx2

__device__ __forceinline__ float bf2f(u16 u){
  union { float f; u32 i; } c; c.i = ((u32)u) << 16; return c.f;
}
__device__ __forceinline__ u16 f2bf(float f){  // round-to-nearest-even
  union { float f; u32 i; } c; c.f = f;
  u32 i = c.i;
  return (u16)((i + 0x7fffu + ((i >> 16) & 1u)) >> 16);
}
__device__ __forceinline__ float sigm(float v){ return 1.f / (1.f + __expf(-v)); }

// packed activation element: low16 = hi bf16, high16 = lo bf16; value = hi + lo
__device__ __forceinline__ u32 packf(float v){
  const u16 hi = f2bf(v);
  const u16 lo = f2bf(v - bf2f(hi));
  return (u32)hi | ((u32)lo << 16);
}
__device__ __forceinline__ float unpackf(u32 w){
  return bf2f((u16)(w & 0xffffu)) + bf2f((u16)(w >> 16));
}

// agent-scope (MALL-coherent) scalar load — used for M (value word of a pair)
__device__ __forceinline__ u32 ald(const u32* p){
  return __hip_atomic_load(p, __ATOMIC_RELAXED, __HIP_MEMORY_SCOPE_AGENT);
}

// pair store: {value, tag} in one dwordx2, agent scope (write-through to MALL)
__device__ __forceinline__ void past(u32* pb, int gi, u32 val, int tag){
  v2u d; d[0] = val; d[1] = (u32)tag;
  asm volatile("global_store_dwordx2 %0, %1, off sc0 sc1"
               :: "v"(pb + 2 * (size_t)gi), "v"(d) : "memory");
}

// ---- batched pair loads: 16 dwordx4 covering 32 (value,tag) pairs ----
// lane covers cols kb+32*ks+{0..7}, ks=0..3; pair stride 8B -> offsets ks*256+{0,16,32,48}
__device__ __forceinline__ void pald16(const u32* p, v4u r[16]){
  asm volatile(
    "global_load_dwordx4 %0, %16, off sc0 sc1\n\t"
    "global_load_dwordx4 %1, %16, off offset:16 sc0 sc1\n\t"
    "global_load_dwordx4 %2, %16, off offset:32 sc0 sc1\n\t"
    "global_load_dwordx4 %3, %16, off offset:48 sc0 sc1\n\t"
    "global_load_dwordx4 %4, %16, off offset:256 sc0 sc1\n\t"
    "global_load_dwordx4 %5, %16, off offset:272 sc0 sc1\n\t"
    "global_load_dwordx4 %6, %16, off offset:288 sc0 sc1\n\t"
    "global_load_dwordx4 %7, %16, off offset:304 sc0 sc1\n\t"
    "global_load_dwordx4 %8, %16, off offset:512 sc0 sc1\n\t"
    "global_load_dwordx4 %9, %16, off offset:528 sc0 sc1\n\t"
    "global_load_dwordx4 %10, %16, off offset:544 sc0 sc1\n\t"
    "global_load_dwordx4 %11, %16, off offset:560 sc0 sc1\n\t"
    "global_load_dwordx4 %12, %16, off offset:768 sc0 sc1\n\t"
    "global_load_dwordx4 %13, %16, off offset:784 sc0 sc1\n\t"
    "global_load_dwordx4 %14, %16, off offset:800 sc0 sc1\n\t"
    "global_load_dwordx4 %15, %16, off offset:816 sc0 sc1\n\t"
    "s_waitcnt vmcnt(0)"
    : "=&v"(r[0]), "=&v"(r[1]), "=&v"(r[2]), "=&v"(r[3]),
      "=&v"(r[4]), "=&v"(r[5]), "=&v"(r[6]), "=&v"(r[7]),
      "=&v"(r[8]), "=&v"(r[9]), "=&v"(r[10]), "=&v"(r[11]),
      "=&v"(r[12]), "=&v"(r[13]), "=&v"(r[14]), "=&v"(r[15])
    : "v"(p) : "memory");
}

// poll until all 32 tags == utag, then deliver values in ald_batch8 layout:
// ar[2ks] = cols kb+32ks+{0..3}, ar[2ks+1] = +{4..7}
__device__ __forceinline__ void poll16(const u32* p, int utag, v4u ar[8]){
  const u32 ut = (u32)utag;
  v4u r[16];
  int tries = 0;
  for (;;){
    pald16(p, r);
    bool ok = true;
#pragma unroll
    for (int i = 0; i < 16; i++) ok &= (r[i][1] == ut) & (r[i][3] == ut);
    if (__all(ok)) break;
    if (++tries > 1) __builtin_amdgcn_s_sleep(2);
  }
#pragma unroll
  for (int ks = 0; ks < 4; ks++){
    ar[2*ks]   = (v4u){ r[4*ks][0],   r[4*ks][2],   r[4*ks+1][0], r[4*ks+1][2] };
    ar[2*ks+1] = (v4u){ r[4*ks+2][0], r[4*ks+2][2], r[4*ks+3][0], r[4*ks+3][2] };
  }
}

struct FragPair { v8s hi; v8s lo; };
// two dwordx4 of packed u32 -> (8 hi bf16, 8 lo bf16)
__device__ __forceinline__ FragPair splitpair(v4u w0, v4u w1){
  union { v8s v; u32 u[4]; } H, L;
#pragma unroll
  for (int i = 0; i < 2; i++){
    H.u[i]     = (w0[2*i] & 0xffffu) | (w0[2*i+1] << 16);
    L.u[i]     = (w0[2*i] >> 16)     | (w0[2*i+1] & 0xffff0000u);
    H.u[2 + i] = (w1[2*i] & 0xffffu) | (w1[2*i+1] << 16);
    L.u[2 + i] = (w1[2*i] >> 16)     | (w1[2*i+1] & 0xffff0000u);
  }
  FragPair f; f.hi = H.v; f.lo = L.v; return f;
}

// ---- mog weight prefetch: ALL 4 k-steps (plain cached loads, static data) ----
struct MogPre { v8s bh[4]; v8s bl[4]; };
__device__ __forceinline__ MogPre mog_pre(const u16* WThi, const u16* WTlo, int cn, int tid){
  const int w = tid >> 6, lane = tid & 63;
  const int mi = lane & 15, q = lane >> 4;
  const int kb = w * 128 + q * 8;
  const u16* bh_p = WThi + (size_t)(cn + mi) * HD + kb;
  const u16* bl_p = WTlo + (size_t)(cn + mi) * HD + kb;
  MogPre pre;
#pragma unroll
  for (int ks = 0; ks < 4; ks++){
    pre.bh[ks] = *(const v8s*)(bh_p + ks * 32);
    pre.bl[ks] = *(const v8s*)(bl_p + ks * 32);
  }
  return pre;
}
// gates: ks=0,1 prefetched for all 4 gate n-tiles
struct GatesPre { v8s bh[4][2]; v8s bl[4][2]; };
__device__ __forceinline__ GatesPre gates_pre(
    const u16* WihThi, const u16* WihTlo,
    const u16* WhhThi, const u16* WhhTlo, int cn, int tid){
  const int w = tid >> 6, lane = tid & 63;
  const int mi = lane & 15, q = lane >> 4;
  const int src = w >> 2;
  const u16* Bh = src ? WhhThi : WihThi;
  const u16* Bl = src ? WhhTlo : WihTlo;
  const int kb = (w & 3) * 256 + q * 8;
  GatesPre g;
#pragma unroll
  for (int nt = 0; nt < 4; nt++){
    const size_t brow = (size_t)(nt * HD + cn + mi) * HD + kb;
#pragma unroll
    for (int ks = 0; ks < 2; ks++){
      g.bh[nt][ks] = *(const v8s*)(Bh + brow + ks * 32);
      g.bl[nt][ks] = *(const v8s*)(Bl + brow + ks * 32);
    }
  }
  return g;
}

// ---- one mogrify matmul phase: O = 2*sigmoid(A @ W) * mult ----
// Sync is tag-in-data: poll exactly the 32 (value,tag) pairs this lane consumes.
// M (multiplier) is a same-thread prior store -> plain agent load of the value word.
__device__ __forceinline__ void mog_phase(
    MogPre pre, const u32* Ap, int utag,
    const float* multx, const u32* Mp, u32* Op, int otag,
    int rm, int cn, int tid, float* cb)
{
  const int w = tid >> 6, lane = tid & 63;
  const int mi = lane & 15, q = lane >> 4;
  const int kb = w * 128 + q * 8;
  const int er = tid >> 4, ec = tid & 15;
  const int gi = (rm + er) * HD + (cn + ec);
  const bool epi = (tid < 256);
  float multv = 0.f; u32 mpack = 0;
  if (epi){
    if (multx) multv = __builtin_nontemporal_load(multx + (size_t)(rm + er) * (SEQ * HD) + (cn + ec));
    else       mpack = ald(Mp + 2 * (size_t)gi);
  }
  v4u ar[8];
  poll16(Ap + 2 * ((size_t)(rm + mi) * HD + kb), utag, ar);

  v4f acc = {0.f, 0.f, 0.f, 0.f};
#pragma unroll
  for (int ks = 0; ks < 4; ks++){
    FragPair a = splitpair(ar[2 * ks], ar[2 * ks + 1]);
    acc = __builtin_amdgcn_mfma_f32_16x16x32_bf16(a.hi, pre.bh[ks], acc, 0, 0, 0);
    acc = __builtin_amdgcn_mfma_f32_16x16x32_bf16(a.hi, pre.bl[ks], acc, 0, 0, 0);
    acc = __builtin_amdgcn_mfma_f32_16x16x32_bf16(a.lo, pre.bh[ks], acc, 0, 0, 0);
  }

  float* dst = cb + w * 1088;            // [w][16][17] partials
#pragma unroll
  for (int r = 0; r < 4; r++) dst[(q * 4 + r) * 17 + mi] = acc[r];
  __syncthreads();
  if (epi){
    float v = 0.f;
#pragma unroll
    for (int w2 = 0; w2 < 8; w2++) v += cb[w2 * 1088 + er * 17 + ec];
    const float mult = multx ? multv : unpackf(mpack);
    past(Op, gi, packf(2.f * sigm(v) * mult), otag);
  }
  __syncthreads();   // protect cb from next phase's partial writes
}

// ---- gates + fused LSTM cell ----
// Whh waves (4-7) poll h2 (i4 output, older -> usually instant);
// Wih waves (0-3) poll x3 (i5 output). Natural producer/consumer overlap.
__device__ __forceinline__ void gates_phase(
    GatesPre gp, const u32* Xp, const u32* Hp, int utag,
    const u16* WihThi, const u16* WihTlo,
    const u16* WhhThi, const u16* WhhTlo,
    const float* bsum, float& creg, u32* Ohp, int otag,
    float* out, bool last,
    int rm, int cn, int tid, float* cb, float* red)
{
  const int w = tid >> 6, lane = tid & 63;
  const int mi = lane & 15, q = lane >> 4;
  const int src = w >> 2;
  const u32* Ap = src ? Hp : Xp;
  const u16* Bh = src ? WhhThi : WihThi;
  const u16* Bl = src ? WhhTlo : WihTlo;
  const int kb = (w & 3) * 256 + q * 8;
  const u16* bh_p[4]; const u16* bl_p[4];
#pragma unroll
  for (int nt = 0; nt < 4; nt++){
    const size_t brow = (size_t)(nt * HD + cn + mi) * HD + kb;
    bh_p[nt] = Bh + brow; bl_p[nt] = Bl + brow;
  }
  const u32* abase = Ap + 2 * ((size_t)(rm + mi) * HD + kb);

  v4f acc[4];
#pragma unroll
  for (int nt = 0; nt < 4; nt++) acc[nt] = (v4f){0.f, 0.f, 0.f, 0.f};

  // first half: ks 0..3 (cols kb..kb+127)
  {
    v4u ar[8];
    poll16(abase, utag, ar);
#pragma unroll
    for (int ks = 0; ks < 4; ks++){
      FragPair a = splitpair(ar[2 * ks], ar[2 * ks + 1]);
#pragma unroll
      for (int nt = 0; nt < 4; nt++){
        v8s bh, bl;
        if (ks < 2){ bh = gp.bh[nt][ks]; bl = gp.bl[nt][ks]; }
        else       { bh = *(const v8s*)(bh_p[nt] + ks * 32);
                     bl = *(const v8s*)(bl_p[nt] + ks * 32); }
        acc[nt] = __builtin_amdgcn_mfma_f32_16x16x32_bf16(a.hi, bh, acc[nt], 0, 0, 0);
        acc[nt] = __builtin_amdgcn_mfma_f32_16x16x32_bf16(a.hi, bl, acc[nt], 0, 0, 0);
        acc[nt] = __builtin_amdgcn_mfma_f32_16x16x32_bf16(a.lo, bh, acc[nt], 0, 0, 0);
      }
    }
  }
  // second half: ks 4..7 (cols kb+128..kb+255); pair offset +128 cols = +256 u32
  {
    v4u ar[8];
    poll16(abase + 256, utag, ar);
#pragma unroll
    for (int ks = 4; ks < 8; ks++){
      FragPair a = splitpair(ar[2 * (ks - 4)], ar[2 * (ks - 4) + 1]);
#pragma unroll
      for (int nt = 0; nt < 4; nt++){
        v8s bh = *(const v8s*)(bh_p[nt] + ks * 32);
        v8s bl = *(const v8s*)(bl_p[nt] + ks * 32);
        acc[nt] = __builtin_amdgcn_mfma_f32_16x16x32_bf16(a.hi, bh, acc[nt], 0, 0, 0);
        acc[nt] = __builtin_amdgcn_mfma_f32_16x16x32_bf16(a.hi, bl, acc[nt], 0, 0, 0);
        acc[nt] = __builtin_amdgcn_mfma_f32_16x16x32_bf16(a.lo, bh, acc[nt], 0, 0, 0);
      }
    }
  }
#pragma unroll
  for (int nt = 0; nt < 4; nt++)
#pragma unroll
    for (int r = 0; r < 4; r++)
      cb[(w * 4 + nt) * 272 + (q * 4 + r) * 17 + mi] = acc[nt][r];
  __syncthreads();
  for (int e = tid; e < 1024; e += NTHR){
    const int qq = e >> 8, rc = e & 255, r = rc >> 4, c = rc & 15;
    float v = 0.f;
#pragma unroll
    for (int w2 = 0; w2 < 8; w2++) v += cb[(w2 * 4 + qq) * 272 + r * 17 + c];
    red[qq * 272 + r * 17 + c] = v;
  }
  __syncthreads();
  if (tid < 256){
    const int r = tid >> 4, c = tid & 15;
    const float g0 = red[0 * 272 + r * 17 + c] + bsum[0];
    const float g1 = red[1 * 272 + r * 17 + c] + bsum[1];
    const float g2 = red[2 * 272 + r * 17 + c] + bsum[2];
    const float g3 = red[3 * 272 + r * 17 + c] + bsum[3];
    const float ig = sigm(g0), fg = sigm(g1), cg = tanhf(g2), og = sigm(g3);
    const float cnew = fg * creg + ig * cg;
    creg = cnew;
    const float h = og * tanhf(cnew);
    const int gi = (rm + r) * HD + (cn + c);
    past(Ohp, gi, packf(h), otag);
    if (last) out[gi] = h;
  }
  __syncthreads();
}

extern "C" __global__ void __launch_bounds__(NTHR, 2)
moglstm_kernel(const float* __restrict__ x, const float* __restrict__ Wih,
               const float* __restrict__ Whh, const float* __restrict__ bih,
               const float* __restrict__ bhh, const float* __restrict__ Q,
               const float* __restrict__ Rw, const float* __restrict__ h0,
               const float* __restrict__ c0, float* __restrict__ out,
               uint8_t* __restrict__ ws)
{
  __shared__ float cb[32 * 272];
  __shared__ float red[4 * 272];
  __shared__ u16 shh[32 * 33], shl[32 * 33];

  // ---- carve workspace: 12 pair buffers, then weights ----
  const size_t SB = (size_t)BATCH * HD * 2;   // u32 per pair buffer (512 KB)
  u32* P = (u32*)ws;
  u32* x1[2] = { P + 0 * SB, P + 1 * SB };
  u32* h1[2] = { P + 2 * SB, P + 3 * SB };
  u32* x2[2] = { P + 4 * SB, P + 5 * SB };
  u32* h2[2] = { P + 6 * SB, P + 7 * SB };
  u32* x3[2] = { P + 8 * SB, P + 9 * SB };
  u32* hst0  = P + 10 * SB;
  u32* hst1  = P + 11 * SB;
  uint8_t* p = (uint8_t*)(P + 12 * SB);
  u16* QThi  = (u16*)p;  p += (size_t)HD * HD * 2;
  u16* QTlo  = (u16*)p;  p += (size_t)HD * HD * 2;
  u16* RThi  = (u16*)p;  p += (size_t)HD * HD * 2;
  u16* RTlo  = (u16*)p;  p += (size_t)HD * HD * 2;
  u16* WihThi = (u16*)p; p += (size_t)4 * HD * HD * 2;
  u16* WihTlo = (u16*)p; p += (size_t)4 * HD * HD * 2;
  u16* WhhThi = (u16*)p; p += (size_t)4 * HD * HD * 2;
  u16* WhhTlo = (u16*)p; p += (size_t)4 * HD * HD * 2;

  const int bid = blockIdx.x, tid = threadIdx.x;
  const int group = bid >> 6, member = bid & 63;
  const int rm = group * 16, cn = member * 16;

  // ---- prep: weights -> hi/lo bf16 transposed; poison pair tags; h0 init ----
  for (int tile = bid; tile < 10240; tile += NBLK){
    const float* W; u16 *Th, *Tl; int N, kt, nt;
    if (tile < 1024)      { W = Q;   Th = QThi;   Tl = QTlo;   N = HD;     int tl = tile;        kt = tl >> 5; nt = tl & 31; }
    else if (tile < 2048) { W = Rw;  Th = RThi;   Tl = RTlo;   N = HD;     int tl = tile - 1024; kt = tl >> 5; nt = tl & 31; }
    else if (tile < 6144) { W = Wih; Th = WihThi; Tl = WihTlo; N = 4 * HD; int tl = tile - 2048; kt = tl >> 7; nt = tl & 127; }
    else                  { W = Whh; Th = WhhThi; Tl = WhhTlo; N = 4 * HD; int tl = tile - 6144; kt = tl >> 7; nt = tl & 127; }
    for (int e = tid; e < 1024; e += NTHR){
      const int ki = e >> 5, nj = e & 31;
      const float v = W[(size_t)(kt * 32 + ki) * N + nt * 32 + nj];
      const u16 hi = f2bf(v);
      shh[ki * 33 + nj] = hi;
      shl[ki * 33 + nj] = f2bf(v - bf2f(hi));
    }
    __syncthreads();
    for (int e = tid; e < 1024; e += NTHR){
      const int ni = e >> 5, kj = e & 31;
      Th[(size_t)(nt * 32 + ni) * HD + kt * 32 + kj] = shh[kj * 33 + ni];
      Tl[(size_t)(nt * 32 + ni) * HD + kt * 32 + kj] = shl[kj * 33 + ni];
    }
    __syncthreads();
  }
  // poison buffers 0..10 (x1..x3 both parities + hst0): tag can never match 0..512
  for (size_t i = (size_t)bid * NTHR + tid; i < 11 * SB; i += (size_t)NBLK * NTHR)
    P[i] = 0xFFFFFFFFu;
  // h0 -> hst1 with tag 0 (read by i1 at t=0 expecting tag 0)
  for (int e = bid * NTHR + tid; e < BATCH * HD; e += NBLK * NTHR){
    hst1[2 * e]     = packf(h0[e]);
    hst1[2 * e + 1] = 0u;
  }
  __threadfence();                       // wbl2: make plain stores MALL-visible
  cooperative_groups::this_grid().sync();  // launch-robust full-grid barrier

  // cell state + bias sums in registers (block<->tile mapping fixed)
  float creg = 0.f;
  float bsum[4] = {0.f, 0.f, 0.f, 0.f};
  if (tid < 256){
    const int r = tid >> 4, c = tid & 15, col = cn + c;
    creg = c0[(rm + r) * HD + col];
#pragma unroll
    for (int qq = 0; qq < 4; qq++) bsum[qq] = bih[qq * HD + col] + bhh[qq * HD + col];
  }

  // ---- recurrence: 4 independent row groups, tag-in-data sync, no flags ----
  MogPre pre = mog_pre(QThi, QTlo, cn, tid);
  for (int t = 0; t < SEQ; t++){
    const int pbit = t & 1;
    const u32* hrd = pbit ? hst0 : hst1;   // h(t-1)
    u32*       hwr = pbit ? hst1 : hst0;   // h(t)
    u32 *x1p = x1[pbit], *h1p = h1[pbit], *x2p = x2[pbit], *h2p = h2[pbit], *x3p = x3[pbit];
    const int tg = t + 1;

    // i1: xt1 = 2s(ht0@Q)*x[:,t,:]
    mog_phase(pre, hrd, t, x + (size_t)t * HD, nullptr, x1p, tg, rm, cn, tid, cb);
    pre = mog_pre(RThi, RTlo, cn, tid);
    // i2: ht1 = 2s(xt1@R)*ht0
    mog_phase(pre, x1p, tg, nullptr, hrd, h1p, tg, rm, cn, tid, cb);
    pre = mog_pre(QThi, QTlo, cn, tid);
    // i3: xt2 = 2s(ht1@Q)*xt1
    mog_phase(pre, h1p, tg, nullptr, x1p, x2p, tg, rm, cn, tid, cb);
    pre = mog_pre(RThi, RTlo, cn, tid);
    // i4: ht2 = 2s(xt2@R)*ht1
    mog_phase(pre, x2p, tg, nullptr, h1p, h2p, tg, rm, cn, tid, cb);
    pre = mog_pre(QThi, QTlo, cn, tid);
    // i5: xt3 = 2s(ht2@Q)*xt2
    mog_phase(pre, h2p, tg, nullptr, x2p, x3p, tg, rm, cn, tid, cb);
    GatesPre gp = gates_pre(WihThi, WihTlo, WhhThi, WhhTlo, cn, tid);
    // gates + cell -> h(t)
    gates_phase(gp, x3p, h2p, tg, WihThi, WihTlo, WhhThi, WhhTlo,
                bsum, creg, hwr, tg, out, (t == SEQ - 1),
                rm, cn, tid, cb, red);
    pre = mog_pre(QThi, QTlo, cn, tid);
  }
}

extern "C" void kernel_launch(void* const* d_in, const int* in_sizes, int n_in,
                              void* d_out, int out_size, void* d_ws, size_t ws_size,
                              hipStream_t stream)
{
  const float* x   = (const float*)d_in[0];
  const float* Wih = (const float*)d_in[1];
  const float* Whh = (const float*)d_in[2];
  const float* bih = (const float*)d_in[3];
  const float* bhh = (const float*)d_in[4];
  const float* Q   = (const float*)d_in[5];
  const float* Rw  = (const float*)d_in[6];
  const float* h0  = (const float*)d_in[7];
  const float* c0  = (const float*)d_in[8];
  float* out = (float*)d_out;
  uint8_t* ws = (uint8_t*)d_ws;
  void* args[] = { &x, &Wih, &Whh, &bih, &bhh, &Q, &Rw, &h0, &c0, &out, &ws };
  hipLaunchCooperativeKernel((void*)moglstm_kernel, dim3(NBLK), dim3(NTHR),
                             args, 0, stream);
}